// Round 15
// baseline (785.116 us; speedup 1.0000x reference)
//
#include <hip/hip_runtime.h>

#define NEG_SLOPE 0.2f
#define BN_EPS 1e-5f

typedef __bf16 bf16x8 __attribute__((ext_vector_type(8)));
typedef float  f32x4  __attribute__((ext_vector_type(4)));
typedef unsigned short ushort8_t __attribute__((ext_vector_type(8)));

__device__ __forceinline__ unsigned short f2bf(float f) {  // RNE f32->bf16
    unsigned int u = __float_as_uint(f);
    unsigned int r = u + 0x7FFFu + ((u >> 16) & 1u);
    return (unsigned short)(r >> 16);
}
__device__ __forceinline__ float bf2f(unsigned short u) {
    return __uint_as_float(((unsigned int)u) << 16);
}
__device__ __forceinline__ void gload16(const void* g, void* l) {
    __builtin_amdgcn_global_load_lds(
        (const __attribute__((address_space(1))) unsigned int*)g,
        (__attribute__((address_space(3))) unsigned int*)l, 16, 0, 0);
}
// device-scope multi-block sync (co-resident grid required)
__device__ __forceinline__ void gsync(int* cnt, int target) {
    __syncthreads();
    if (threadIdx.x == 0) {
        __threadfence();
        atomicAdd(cnt, 1);
        while (atomicAdd(cnt, 0) < target) { asm volatile("s_sleep 1"); }
        __threadfence();
    }
    __syncthreads();
}

// ================= FRONT: prep | scan+elr | scatter | gat =================
__global__ __launch_bounds__(256, 4)
void front(const float* __restrict__ x, const int* __restrict__ src,
           const int* __restrict__ dst,
           const float* __restrict__ fc_w, const float* __restrict__ w2,
           const float* __restrict__ attn_l, const float* __restrict__ attn_r,
           unsigned short* __restrict__ xbf, unsigned short* __restrict__ fcwbf,
           unsigned short* __restrict__ w2bf, float* __restrict__ proj,
           int* __restrict__ counts, int* __restrict__ bsum,
           int* __restrict__ row_ptr, int* __restrict__ cursor,
           int* __restrict__ esrc, float* __restrict__ el, float* __restrict__ er,
           unsigned short* __restrict__ xagg, int* __restrict__ cnt,
           int N, int E, int NB)
{
    const int bid = blockIdx.x, tid = threadIdx.x;
    const int grid = gridDim.x;
    const int NH = N * 8;
    const int totX4 = (N * 64) / 4;
    const int bCvtx = (totX4 + 255) / 256;
    const int bHist = bCvtx + (E + 1023) / 1024;
    const int bFcw  = bHist + 32;
    const int bW2   = bFcw + 64;
    const int nPrep = bW2 + 1;

    // ---- phase 0: prep roles ----
    for (int c = bid; c < nPrep; c += grid) {
        if (c < bCvtx) {
            int i4 = c * 256 + tid;
            if (i4 < totX4) {
                float4 v = *(const float4*)(x + (size_t)i4 * 4);
                ushort4 o = {f2bf(v.x), f2bf(v.y), f2bf(v.z), f2bf(v.w)};
                *(ushort4*)(xbf + (size_t)i4 * 4) = o;
            }
        } else if (c < bHist) {
            int base = (c - bCvtx) * 1024 + tid;
            #pragma unroll
            for (int k = 0; k < 4; ++k) {
                int e = base + k * 256;
                if (e < E) atomicAdd(&counts[dst[e]], 1);
            }
        } else if (c < bFcw) {
            int i4 = (c - bHist) * 256 + tid;
            if (i4 < 8192) {
                float4 v = *(const float4*)(fc_w + (size_t)i4 * 4);
                ushort4 o = {f2bf(v.x), f2bf(v.y), f2bf(v.z), f2bf(v.w)};
                *(ushort4*)(fcwbf + (size_t)i4 * 4) = o;
            }
        } else if (c < bW2) {
            int i4 = (c - bFcw) * 256 + tid;
            if (i4 < 16384) {
                float4 v = *(const float4*)(w2 + (size_t)i4 * 4);
                ushort4 o = {f2bf(v.x), f2bf(v.y), f2bf(v.z), f2bf(v.w)};
                *(ushort4*)(w2bf + (size_t)i4 * 4) = o;
            }
        } else {
            for (int t2 = tid; t2 < 512; t2 += 256) {
                int h = t2 >> 6, k = t2 & 63;
                float al = 0.f, ar = 0.f;
                for (int d = 0; d < 64; ++d) {
                    float w = fc_w[(size_t)(h * 64 + d) * 64 + k];
                    al = fmaf(attn_l[h * 64 + d], w, al);
                    ar = fmaf(attn_r[h * 64 + d], w, ar);
                }
                proj[t2] = al;
                proj[512 + t2] = ar;
            }
        }
    }
    gsync(cnt, grid);

    // ---- phase 1: scan (blocks < NB) | elr (others) ----
    if (bid < NB) {
        __shared__ int sm[256];
        __shared__ int rm[256];
        int i = bid * 256 + tid;
        int v = (i < N) ? counts[i] : 0;
        sm[tid] = v;
        __syncthreads();
        #pragma unroll
        for (int d = 1; d < 256; d <<= 1) {
            int t = (tid >= d) ? sm[tid - d] : 0;
            __syncthreads();
            sm[tid] += t;
            __syncthreads();
        }
        if (tid == 255) atomicExch(&bsum[bid], sm[255] | 0x40000000);
        int myagg = 0;
        if (tid < bid) {
            int vv;
            do { vv = atomicAdd(&bsum[tid], 0); } while (!(vv & 0x40000000));
            myagg = vv & 0x3FFFFFFF;
        }
        rm[tid] = myagg;
        __syncthreads();
        #pragma unroll
        for (int d = 128; d > 0; d >>= 1) {
            if (tid < d) rm[tid] += rm[tid + d];
            __syncthreads();
        }
        int pre = rm[0];
        if (i < N) {
            int w = sm[tid] + pre;
            row_ptr[i + 1] = w;
            cursor[i + 1] = w;
        }
        if (i == 0) { row_ptr[0] = 0; cursor[0] = 0; }
    } else {
        const int EC = (NH + 255) / 256;
        for (int c = bid - NB; c < EC; c += grid - NB) {
            int idx = c * 256 + tid;
            if (idx >= NH) continue;
            int h = idx & 7, n = idx >> 3;
            const ushort8_t* f = (const ushort8_t*)(xbf + (size_t)n * 64);
            const float* pl = proj + h * 64;
            const float* pr = proj + 512 + h * 64;
            float sl = 0.f, sr = 0.f;
            #pragma unroll
            for (int i8 = 0; i8 < 8; ++i8) {
                ushort8_t v = f[i8];
                #pragma unroll
                for (int t = 0; t < 8; ++t) {
                    float fv = bf2f(v[t]);
                    sl = fmaf(fv, pl[i8 * 8 + t], sl);
                    sr = fmaf(fv, pr[i8 * 8 + t], sr);
                }
            }
            el[idx] = sl;
            er[idx] = sr;
        }
    }
    gsync(cnt, 2 * grid);

    // ---- phase 2: scatter edges ----
    {
        const int SC = (E + 255) / 256;
        for (int c = bid; c < SC; c += grid) {
            int e = c * 256 + tid;
            if (e < E) {
                int p = atomicAdd(&cursor[dst[e]], 1);
                esrc[p] = src[e];
            }
        }
    }
    gsync(cnt, 3 * grid);

    // ---- phase 3: gat aggregate ----
    {
        const int NG = (N + 3) / 4;
        const int lane = tid & 63;
        const int h = lane >> 3, j = lane & 7;
        for (int g = bid; g < NG; g += grid) {
            int node = g * 4 + (tid >> 6);
            if (node >= N) continue;
            const int beg = row_ptr[node], end = row_ptr[node + 1];
            const float er_n = er[node * 8 + h];
            float denom = 0.f;
            float a[8] = {};
            int s_cur = (beg < end) ? esrc[beg] : 0;
            for (int k = beg; k < end; ++k) {
                int s_nxt = (k + 1 < end) ? esrc[k + 1] : 0;
                float elv = el[s_cur * 8 + h];
                ushort8_t fv = *(const ushort8_t*)(xbf + (size_t)s_cur * 64 + j * 8);
                float v = elv + er_n;
                v = (v > 0.f) ? v : NEG_SLOPE * v;
                float z = __expf(v);
                denom += z;
                #pragma unroll
                for (int t = 0; t < 8; ++t) a[t] = fmaf(z, bf2f(fv[t]), a[t]);
                s_cur = s_nxt;
            }
            float inv = (end > beg) ? 1.f / denom : 0.f;
            ushort8_t o;
            #pragma unroll
            for (int t = 0; t < 8; ++t) o[t] = f2bf(a[t] * inv);
            *(ushort8_t*)(xagg + (size_t)node * 512 + lane * 8) = o;
        }
    }
}

// ================= MID: bn1_stats (grid-stride) | fold =================
__global__ __launch_bounds__(256, 4)
void mid(const unsigned short* __restrict__ Xa, const unsigned short* __restrict__ Fw,
         const float* __restrict__ gat_bias,
         const float* __restrict__ w1, const float* __restrict__ fc_w,
         const float* __restrict__ gamma, const float* __restrict__ beta,
         const float* __restrict__ b1,
         float* __restrict__ sums1, unsigned short* __restrict__ wtil,
         float* __restrict__ b1p, int* __restrict__ cnt, int M, float invM)
{
    __shared__ alignas(16) char msm[26624];   // phase1: Asm 16K + Bsm 8K; phase2: sF 16.64K + sa
    __shared__ float reds[4][64], redq[4][64];
    const int bid = blockIdx.x, tid = threadIdx.x;
    const int grid = gridDim.x;
    const int lane = tid & 63, wave = tid >> 6;

    // ---- phase 1: BN1 stats ----
    {
        char* Asm = msm;
        char* Bsm = msm + 16384;
        const int lr = lane >> 3, lk = ((lane & 7) ^ lr) * 8;
        const int nJobs = ((M + 127) / 128) * 8;
        for (int job = bid; job < nJobs; job += grid) {
            const int bm = (job >> 3) * 128;
            const int head = job & 7;
            __syncthreads();
            #pragma unroll
            for (int it = 0; it < 4; ++it) {
                int seg = wave * 4 + it;
                gload16(Xa + (size_t)(bm + seg * 8 + lr) * 512 + head * 64 + lk, Asm + seg * 1024);
            }
            #pragma unroll
            for (int it = 0; it < 2; ++it) {
                int seg = wave * 2 + it;
                gload16(Fw + (size_t)(head * 64 + seg * 8 + lr) * 64 + lk, Bsm + seg * 1024);
            }
            __syncthreads();
            f32x4 acc[2][4] = {};
            #pragma unroll
            for (int kk = 0; kk < 2; ++kk) {
                int kg = kk * 4 + (lane >> 4);
                bf16x8 a[2], b[4];
                #pragma unroll
                for (int i = 0; i < 2; ++i) {
                    int row = wave * 32 + i * 16 + (lane & 15);
                    a[i] = *(const bf16x8*)(Asm + row * 128 + ((kg ^ (row & 7)) << 4));
                }
                #pragma unroll
                for (int j = 0; j < 4; ++j) {
                    int row = j * 16 + (lane & 15);
                    b[j] = *(const bf16x8*)(Bsm + row * 128 + ((kg ^ (row & 7)) << 4));
                }
                #pragma unroll
                for (int i = 0; i < 2; ++i)
                    #pragma unroll
                    for (int j = 0; j < 4; ++j)
                        acc[i][j] = __builtin_amdgcn_mfma_f32_16x16x32_bf16(a[i], b[j], acc[i][j], 0, 0, 0);
            }
            float s4[4] = {}, q4[4] = {};
            #pragma unroll
            for (int j = 0; j < 4; ++j) {
                int col = j * 16 + (lane & 15);
                float bias = gat_bias[head * 64 + col];
                #pragma unroll
                for (int i = 0; i < 2; ++i)
                    #pragma unroll
                    for (int r = 0; r < 4; ++r) {
                        int gm = bm + wave * 32 + i * 16 + (lane >> 4) * 4 + r;
                        if (gm < M) {
                            float vq = bf2f(f2bf(acc[i][j][r] + bias));
                            s4[j] += vq; q4[j] += vq * vq;
                        }
                    }
            }
            #pragma unroll
            for (int j = 0; j < 4; ++j) {
                s4[j] += __shfl_xor(s4[j], 16); q4[j] += __shfl_xor(q4[j], 16);
                s4[j] += __shfl_xor(s4[j], 32); q4[j] += __shfl_xor(q4[j], 32);
            }
            if (lane < 16) {
                #pragma unroll
                for (int j = 0; j < 4; ++j) {
                    reds[wave][j * 16 + lane] = s4[j];
                    redq[wave][j * 16 + lane] = q4[j];
                }
            }
            __syncthreads();
            if (wave == 0 && lane < 16) {
                #pragma unroll
                for (int j = 0; j < 4; ++j) {
                    int c = j * 16 + lane;
                    atomicAdd(&sums1[head * 64 + c], reds[0][c] + reds[1][c] + reds[2][c] + reds[3][c]);
                    atomicAdd(&sums1[512 + head * 64 + c], redq[0][c] + redq[1][c] + redq[2][c] + redq[3][c]);
                }
            }
        }
    }
    gsync(cnt, grid);

    // ---- phase 2: fold (<=1 job per block) ----
    for (int job = bid; job < 320; job += grid) {
        if (job < 64) {
            float (*sF)[65] = (float(*)[65])msm;             // 16.64KB
            float* sa = (float*)(msm + 16640);               // 256B
            int ot = job >> 3, h = job & 7;
            if (tid < 64) {
                int c = h * 64 + tid;
                float mu = sums1[c] * invM;
                float var = sums1[512 + c] * invM - mu * mu;
                sa[tid] = gamma[c] * rsqrtf(var + BN_EPS);
            }
            for (int e = 0; e < 16; ++e) {
                int idx = tid * 16 + e;
                int d = idx >> 6, k = idx & 63;
                sF[k][d] = fc_w[(size_t)(h * 64 + d) * 64 + k];
            }
            __syncthreads();
            int ol = tid >> 1, half = tid & 1;
            int o = ot * 128 + ol;
            int kbase = half * 32;
            float acc[32];
            #pragma unroll
            for (int i = 0; i < 32; ++i) acc[i] = 0.f;
            const float* wrow = w1 + (size_t)o * 512 + h * 64;
            #pragma unroll
            for (int dc = 0; dc < 4; ++dc) {
                float wa[16];
                #pragma unroll
                for (int d = 0; d < 16; ++d) wa[d] = wrow[dc * 16 + d] * sa[dc * 16 + d];
                #pragma unroll
                for (int kk2 = 0; kk2 < 32; ++kk2) {
                    float s = acc[kk2];
                    #pragma unroll
                    for (int d = 0; d < 16; ++d) s = fmaf(wa[d], sF[kbase + kk2][dc * 16 + d], s);
                    acc[kk2] = s;
                }
            }
            unsigned int* orow = (unsigned int*)(wtil + (size_t)o * 512 + h * 64 + kbase);
            #pragma unroll
            for (int i = 0; i < 16; ++i)
                orow[i] = (unsigned int)f2bf(acc[2 * i]) | ((unsigned int)f2bf(acc[2 * i + 1]) << 16);
        } else {
            float* ss = (float*)msm;                          // 2KB
            for (int c = tid; c < 512; c += 256) {
                float mu = sums1[c] * invM;
                float var = sums1[512 + c] * invM - mu * mu;
                float a = gamma[c] * rsqrtf(var + BN_EPS);
                ss[c] = beta[c] + a * (gat_bias[c] - mu);
            }
            __syncthreads();
            int o = (job - 64) * 4 + wave;
            const float* wrow = w1 + (size_t)o * 512 + lane * 8;
            float p = 0.f;
            #pragma unroll
            for (int t2 = 0; t2 < 8; ++t2) p = fmaf(wrow[t2], ss[lane * 8 + t2], p);
            #pragma unroll
            for (int d = 1; d < 64; d <<= 1) p += __shfl_xor(p, d);
            if (lane == 0) b1p[o] = b1[o] + p;
        }
    }
}

// ---------------- GEMM2 + partial GEMM3, bf16 P-partial stores (unchanged) ----------------
__global__ __launch_bounds__(256)
void gemm2p(const unsigned short* __restrict__ A,
            const unsigned short* __restrict__ B,
            const unsigned short* __restrict__ W2,
            const float* __restrict__ b1p,
            unsigned short* __restrict__ P, int M)
{
    __shared__ alignas(16) char smem[49152];
    char* Abuf0 = smem;
    char* Abuf1 = smem + 16384;
    char* Bbuf  = smem + 32768;
    char* TR   = smem;
    char* Wbuf = smem + 32768;
    char* PK   = smem + 32768;

    const int tid = threadIdx.x, lane = tid & 63, wave = tid >> 6;
    const int wr = wave >> 1, wc = wave & 1;
    const int lr = lane >> 3, lk = ((lane & 7) ^ lr) * 8;

    int bid = blockIdx.x;
    int wgid = (bid & 7) * 391 + (bid >> 3);
    const int bm = (wgid >> 3) * 128;
    const int t  = wgid & 7;
    const int bn = t * 128;

    #pragma unroll
    for (int it = 0; it < 4; ++it) {
        int seg = wave * 4 + it;
        gload16(A + (size_t)(bm + seg * 8 + lr) * 512 + lk, Abuf0 + seg * 1024);
    }

    f32x4 acc[4][4] = {};
    #pragma unroll
    for (int ks = 0; ks < 8; ++ks) {
        const int k0 = ks * 64;
        #pragma unroll
        for (int it = 0; it < 4; ++it) {
            int seg = wave * 4 + it;
            gload16(B + (size_t)(bn + seg * 8 + lr) * 512 + k0 + lk, Bbuf + seg * 1024);
        }
        if (ks < 7) {
            char* An = (ks & 1) ? Abuf0 : Abuf1;
            #pragma unroll
            for (int it = 0; it < 4; ++it) {
                int seg = wave * 4 + it;
                gload16(A + (size_t)(bm + seg * 8 + lr) * 512 + (k0 + 64) + lk, An + seg * 1024);
            }
            asm volatile("s_waitcnt vmcnt(4)" ::: "memory");
        } else {
            asm volatile("s_waitcnt vmcnt(0)" ::: "memory");
        }
        __builtin_amdgcn_s_barrier();
        __builtin_amdgcn_sched_barrier(0);
        const char* Ac = (ks & 1) ? Abuf1 : Abuf0;
        #pragma unroll
        for (int kk = 0; kk < 2; ++kk) {
            int kg = kk * 4 + (lane >> 4);
            bf16x8 a[4], b[4];
            #pragma unroll
            for (int i = 0; i < 4; ++i) {
                int row = wr * 64 + i * 16 + (lane & 15);
                a[i] = *(const bf16x8*)(Ac + row * 128 + ((kg ^ (row & 7)) << 4));
            }
            #pragma unroll
            for (int j = 0; j < 4; ++j) {
                int row = wc * 64 + j * 16 + (lane & 15);
                b[j] = *(const bf16x8*)(Bbuf + row * 128 + ((kg ^ (row & 7)) << 4));
            }
            #pragma unroll
            for (int i = 0; i < 4; ++i)
                #pragma unroll
                for (int j = 0; j < 4; ++j)
                    acc[i][j] = __builtin_amdgcn_mfma_f32_16x16x32_bf16(a[i], b[j], acc[i][j], 0, 0, 0);
        }
        __builtin_amdgcn_sched_barrier(0);
        __builtin_amdgcn_s_barrier();
        __builtin_amdgcn_sched_barrier(0);
    }

    #pragma unroll
    for (int j = 0; j < 4; ++j) {
        int c = wc * 64 + j * 16 + (lane & 15);
        float bs = b1p[bn + c];
        #pragma unroll
        for (int i = 0; i < 4; ++i)
            #pragma unroll
            for (int r = 0; r < 4; ++r) {
                int rw = wr * 64 + i * 16 + (lane >> 4) * 4 + r;
                float v = fmaxf(acc[i][j][r] + bs, 0.f);
                *(unsigned short*)(TR + rw * 256 + (((c >> 3) ^ (rw & 7)) << 4) + (c & 7) * 2) = f2bf(v);
            }
    }
    #pragma unroll
    for (int it = 0; it < 4; ++it) {
        int oc = wave * 16 + it * 4 + (lane >> 4);
        int g = lane & 15;
        gload16(W2 + (size_t)oc * 1024 + bn + ((g ^ (oc & 7))) * 8, Wbuf + (wave * 4 + it) * 1024);
    }
    __syncthreads();

    f32x4 pacc[2][4] = {};
    #pragma unroll
    for (int ks = 0; ks < 4; ++ks) {
        int kg2 = ks * 4 + (lane >> 4);
        #pragma unroll
        for (int i = 0; i < 2; ++i) {
            int arow = wave * 32 + i * 16 + (lane & 15);
            bf16x8 av = *(const bf16x8*)(TR + arow * 256 + ((kg2 ^ (arow & 7)) << 4));
            #pragma unroll
            for (int j = 0; j < 4; ++j) {
                int oc = j * 16 + (lane & 15);
                bf16x8 bv = *(const bf16x8*)(Wbuf + oc * 256 + ((kg2 ^ (oc & 7)) << 4));
                pacc[i][j] = __builtin_amdgcn_mfma_f32_16x16x32_bf16(av, bv, pacc[i][j], 0, 0, 0);
            }
        }
    }
    __syncthreads();

    #pragma unroll
    for (int i = 0; i < 2; ++i)
        #pragma unroll
        for (int j = 0; j < 4; ++j)
            #pragma unroll
            for (int r = 0; r < 4; ++r) {
                int row = wave * 32 + i * 16 + (lane >> 4) * 4 + r;
                int col = j * 16 + (lane & 15);
                *(unsigned short*)(PK + row * 128 + col * 2) = f2bf(pacc[i][j][r]);
            }
    __syncthreads();
    unsigned short* Pt = P + (size_t)t * M * 64;
    #pragma unroll
    for (int it = 0; it < 4; ++it) {
        int u = it * 256 + tid;
        int row = u >> 3, g8 = u & 7;
        int gm = bm + row;
        if (gm < M) {
            uint4 v = *(const uint4*)(PK + row * 128 + g8 * 16);
            *(uint4*)(Pt + (size_t)gm * 64 + g8 * 8) = v;
        }
    }
}

// ================= BACK: reduce+BN2 stats | BN2 apply =================
__global__ __launch_bounds__(256, 8)
void back(const unsigned short* __restrict__ P, const float* __restrict__ b2,
          float* __restrict__ out, const float* __restrict__ gamma,
          const float* __restrict__ beta, float* __restrict__ sums2,
          int* __restrict__ cnt, int M, float invM)
{
    __shared__ float ls[256], lq[256];
    const int bid = blockIdx.x, grid = gridDim.x;
    int c = threadIdx.x & 63, g = threadIdx.x >> 6;
    const size_t S = (size_t)M * 64;
    {
        float bias = b2[c];
        float s = 0.f, q = 0.f;
        for (int r = bid * 4 + g; r < M; r += grid * 4) {
            size_t idx = (size_t)r * 64 + c;
            float v = bias;
            #pragma unroll
            for (int t = 0; t < 8; ++t) v += bf2f(P[t * S + idx]);
            out[idx] = v;
            s += v; q += v * v;
        }
        ls[threadIdx.x] = s; lq[threadIdx.x] = q;
        __syncthreads();
        if (g == 0) {
            s = ls[c] + ls[64 + c] + ls[128 + c] + ls[192 + c];
            q = lq[c] + lq[64 + c] + lq[128 + c] + lq[192 + c];
            atomicAdd(&sums2[c], s);
            atomicAdd(&sums2[64 + c], q);
        }
    }
    gsync(cnt, grid);
    {
        float mu = sums2[c] * invM;
        float var = sums2[64 + c] * invM - mu * mu;
        float a = gamma[c] * rsqrtf(var + BN_EPS);
        float b = beta[c] - a * mu;
        for (int r = bid * 4 + g; r < M; r += grid * 4) {
            size_t i = (size_t)r * 64 + c;
            out[i] = fmaf(a, out[i], b);
        }
    }
}

extern "C" void kernel_launch(void* const* d_in, const int* in_sizes, int n_in,
                              void* d_out, int out_size, void* d_ws, size_t ws_size,
                              hipStream_t stream)
{
    const float* x         = (const float*)d_in[0];
    const int*   src       = (const int*)d_in[1];
    const int*   dst       = (const int*)d_in[2];
    const float* fc_w      = (const float*)d_in[3];
    const float* attn_l    = (const float*)d_in[4];
    const float* attn_r    = (const float*)d_in[5];
    const float* gat_bias  = (const float*)d_in[6];
    const float* bn1_gamma = (const float*)d_in[7];
    const float* bn1_beta  = (const float*)d_in[8];
    const float* w1        = (const float*)d_in[9];
    const float* b1        = (const float*)d_in[10];
    const float* w2        = (const float*)d_in[11];
    const float* b2        = (const float*)d_in[12];
    const float* bn2_gamma = (const float*)d_in[13];
    const float* bn2_beta  = (const float*)d_in[14];
    float* out = (float*)d_out;

    const int D = 64, HD = 512, HID = 1024;
    const int N = in_sizes[0] / D;      // 50000
    const int E = in_sizes[1];          // 400000
    const int NH = N * 8;
    const int NB = (N + 255) / 256;     // 196
    const int Mpad = ((N + 127) / 128) * 128 + 128;  // 50176

    size_t off = 0;
    auto alloc = [&](size_t bytes) -> void* {
        void* p = (char*)d_ws + off;
        off += (bytes + 255) & ~(size_t)255;
        return p;
    };
    unsigned short* xagg = (unsigned short*)alloc((size_t)Mpad * HD * 2);
    unsigned short* P    = (unsigned short*)alloc((size_t)8 * N * D * 2);
    unsigned short* xbf  = (unsigned short*)alloc((size_t)N * D * 2);
    unsigned short* fcwbf = (unsigned short*)alloc((size_t)HD * D * 2);
    unsigned short* wtil = (unsigned short*)alloc((size_t)HID * HD * 2);
    unsigned short* w2bf = (unsigned short*)alloc((size_t)D * HID * 2);
    float* b1p   = (float*)alloc(HID * 4);
    float* proj  = (float*)alloc(2 * 512 * 4);
    float* el    = (float*)alloc((size_t)NH * 4);
    float* er    = (float*)alloc((size_t)NH * 4);
    // contiguous zero region: counts | sums1 | sums2 | bsum | sync counters
    char* zbase  = (char*)d_ws + off;
    int* counts  = (int*)alloc((size_t)N * 4);
    float* sums1 = (float*)alloc(2 * 512 * 4);
    float* sums2 = (float*)alloc(2 * 64 * 4);
    int* bsum    = (int*)alloc(256 * 4);
    int* cnts    = (int*)alloc(3 * 256);   // 3 counters, cache-line separated
    size_t zbytes = ((char*)d_ws + off) - zbase;
    int* row_ptr = (int*)alloc((size_t)(N + 1) * 4);
    int* cursor  = (int*)alloc((size_t)(N + 1) * 4);
    int* esrc    = (int*)alloc((size_t)E * 4);
    (void)ws_size; (void)n_in; (void)out_size;

    int* cnt_front = cnts;
    int* cnt_mid   = cnts + 64;
    int* cnt_back  = cnts + 128;

    // 1) zero counts+sums+bsum+counters
    hipMemsetAsync(zbase, 0, zbytes, stream);

    // 2) FRONT: prep | scan+elr | scatter | gat   (960 blocks, 4/CU guaranteed)
    front<<<960, 256, 0, stream>>>(x, src, dst, fc_w, w2, attn_l, attn_r,
                                   xbf, fcwbf, w2bf, proj, counts, bsum,
                                   row_ptr, cursor, esrc, el, er, xagg,
                                   cnt_front, N, E, NB);

    // 3) MID: bn1_stats | fold   (768 blocks, 26KB LDS -> >=4/CU)
    mid<<<768, 256, 0, stream>>>(xagg, fcwbf, gat_bias, w1, fc_w,
                                 bn1_gamma, bn1_beta, b1,
                                 sums1, wtil, b1p, cnt_mid, N, 1.f / N);

    // 4) GEMM2 + partial GEMM3 -> bf16 P partials
    {
        int nwg = ((N + 127) / 128) * 8;  // 3128
        gemm2p<<<nwg, 256, 0, stream>>>(xagg, wtil, w2bf, b1p, P, N);
    }

    // 5) BACK: reduce+BN2 stats | apply   (1024 blocks, 8/CU guaranteed)
    back<<<1024, 256, 0, stream>>>(P, b2, out, bn2_gamma, bn2_beta, sums2,
                                   cnt_back, N, 1.f / N);
}

// Round 16
// 290.302 us; speedup vs baseline: 2.7045x; 2.7045x over previous
//
#include <hip/hip_runtime.h>

#define NEG_SLOPE 0.2f
#define BN_EPS 1e-5f

typedef __bf16 bf16x8 __attribute__((ext_vector_type(8)));
typedef float  f32x4  __attribute__((ext_vector_type(4)));
typedef unsigned short ushort8_t __attribute__((ext_vector_type(8)));

__device__ __forceinline__ unsigned short f2bf(float f) {  // RNE f32->bf16
    unsigned int u = __float_as_uint(f);
    unsigned int r = u + 0x7FFFu + ((u >> 16) & 1u);
    return (unsigned short)(r >> 16);
}
__device__ __forceinline__ float bf2f(unsigned short u) {
    return __uint_as_float(((unsigned int)u) << 16);
}
__device__ __forceinline__ void gload16(const void* g, void* l) {
    __builtin_amdgcn_global_load_lds(
        (const __attribute__((address_space(1))) unsigned int*)g,
        (__attribute__((address_space(3))) unsigned int*)l, 16, 0, 0);
}

// ---------------- prep: cvt_x | hist | cvt_fcw | cvt_w2 | build_proj ----
__global__ __launch_bounds__(256)
void prep(const float* __restrict__ x, const int* __restrict__ dst,
          const float* __restrict__ fc_w, const float* __restrict__ w2,
          const float* __restrict__ attn_l, const float* __restrict__ attn_r,
          unsigned short* __restrict__ xbf, unsigned short* __restrict__ fcwbf,
          unsigned short* __restrict__ w2bf, float* __restrict__ proj,
          int* __restrict__ counts, int totX4, int E,
          int bCvtx, int bHist, int bFcw, int bW2)
{
    const int bid = blockIdx.x, tid = threadIdx.x;
    if (bid < bCvtx) {
        int i4 = bid * 256 + tid;
        if (i4 < totX4) {
            float4 v = *(const float4*)(x + (size_t)i4 * 4);
            ushort4 o = {f2bf(v.x), f2bf(v.y), f2bf(v.z), f2bf(v.w)};
            *(ushort4*)(xbf + (size_t)i4 * 4) = o;
        }
    } else if (bid < bHist) {
        int base = (bid - bCvtx) * 1024 + tid;
        #pragma unroll
        for (int k = 0; k < 4; ++k) {
            int e = base + k * 256;
            if (e < E) atomicAdd(&counts[dst[e]], 1);
        }
    } else if (bid < bFcw) {
        int i4 = (bid - bHist) * 256 + tid;       // 512*64/4 = 8192
        if (i4 < 8192) {
            float4 v = *(const float4*)(fc_w + (size_t)i4 * 4);
            ushort4 o = {f2bf(v.x), f2bf(v.y), f2bf(v.z), f2bf(v.w)};
            *(ushort4*)(fcwbf + (size_t)i4 * 4) = o;
        }
    } else if (bid < bW2) {
        int i4 = (bid - bFcw) * 256 + tid;        // 64*1024/4 = 16384
        if (i4 < 16384) {
            float4 v = *(const float4*)(w2 + (size_t)i4 * 4);
            ushort4 o = {f2bf(v.x), f2bf(v.y), f2bf(v.z), f2bf(v.w)};
            *(ushort4*)(w2bf + (size_t)i4 * 4) = o;
        }
    } else {
        for (int t2 = tid; t2 < 512; t2 += 256) {
            int h = t2 >> 6, k = t2 & 63;
            float al = 0.f, ar = 0.f;
            for (int d = 0; d < 64; ++d) {
                float w = fc_w[(size_t)(h * 64 + d) * 64 + k];
                al = fmaf(attn_l[h * 64 + d], w, al);
                ar = fmaf(attn_r[h * 64 + d], w, ar);
            }
            proj[t2] = al;
            proj[512 + t2] = ar;
        }
    }
}

// ---- scan (single-pass lookback) + elr multi-role ----
// bsum must be zero-initialized. Aggregates carry flag bit 0x40000000.
__global__ __launch_bounds__(256)
void scan_elr(const int* __restrict__ counts, int* __restrict__ bsum,
              int* __restrict__ row_ptr, int* __restrict__ cursor, int N, int NB,
              const unsigned short* __restrict__ xbf, const float* __restrict__ proj,
              float* __restrict__ el, float* __restrict__ er, int NH)
{
    if ((int)blockIdx.x < NB) {
        __shared__ int sm[256];
        __shared__ int rm[256];
        int i = blockIdx.x * 256 + threadIdx.x;
        int v = (i < N) ? counts[i] : 0;
        sm[threadIdx.x] = v;
        __syncthreads();
        #pragma unroll
        for (int d = 1; d < 256; d <<= 1) {
            int t = (threadIdx.x >= d) ? sm[threadIdx.x - d] : 0;
            __syncthreads();
            sm[threadIdx.x] += t;
            __syncthreads();
        }
        // publish this block's aggregate (value carries its own ready-flag)
        if (threadIdx.x == 255)
            atomicExch(&bsum[blockIdx.x], sm[255] | 0x40000000);
        // lookback: thread t (< blockIdx.x) waits for block t's aggregate
        int myagg = 0;
        if ((int)threadIdx.x < (int)blockIdx.x) {
            int vv;
            do { vv = atomicAdd(&bsum[threadIdx.x], 0); } while (!(vv & 0x40000000));
            myagg = vv & 0x3FFFFFFF;
        }
        rm[threadIdx.x] = myagg;
        __syncthreads();
        #pragma unroll
        for (int d = 128; d > 0; d >>= 1) {
            if (threadIdx.x < d) rm[threadIdx.x] += rm[threadIdx.x + d];
            __syncthreads();
        }
        int pre = rm[0];
        if (i < N) {
            int w = sm[threadIdx.x] + pre;
            row_ptr[i + 1] = w;
            cursor[i + 1] = w;
        }
        if (i == 0) { row_ptr[0] = 0; cursor[0] = 0; }
    } else {
        int idx = (blockIdx.x - NB) * 256 + threadIdx.x;  // n*8 + h
        if (idx >= NH) return;
        int h = idx & 7, n = idx >> 3;
        const ushort8_t* f = (const ushort8_t*)(xbf + (size_t)n * 64);
        const float* pl = proj + h * 64;
        const float* pr = proj + 512 + h * 64;
        float sl = 0.f, sr = 0.f;
        #pragma unroll
        for (int i8 = 0; i8 < 8; ++i8) {
            ushort8_t v = f[i8];
            #pragma unroll
            for (int t = 0; t < 8; ++t) {
                float fv = bf2f(v[t]);
                sl = fmaf(fv, pl[i8 * 8 + t], sl);
                sr = fmaf(fv, pr[i8 * 8 + t], sr);
            }
        }
        el[idx] = sl;
        er[idx] = sr;
    }
}

__global__ void scatter_edges(const int* __restrict__ src, const int* __restrict__ dst,
                              int* __restrict__ cursor, int* __restrict__ esrc, int E) {
    int e = blockIdx.x * 256 + threadIdx.x;
    if (e < E) {
        int p = atomicAdd(&cursor[dst[e]], 1);
        esrc[p] = src[e];
    }
}

// ---- fused GAT softmax + weighted aggregate of X (single pass) ----
__global__ __launch_bounds__(256)
void gat_aggregate(const int* __restrict__ row_ptr, const int* __restrict__ esrc,
                   const float* __restrict__ el, const float* __restrict__ er,
                   const unsigned short* __restrict__ xb, unsigned short* __restrict__ xagg,
                   int N)
{
    int node = blockIdx.x * 4 + (threadIdx.x >> 6);
    if (node >= N) return;
    const int lane = threadIdx.x & 63;
    const int h = lane >> 3, j = lane & 7;
    const int beg = row_ptr[node], end = row_ptr[node + 1];
    const float er_n = er[node * 8 + h];

    float denom = 0.f;
    float a[8] = {};
    int s_cur = (beg < end) ? esrc[beg] : 0;
    for (int k = beg; k < end; ++k) {
        int s_nxt = (k + 1 < end) ? esrc[k + 1] : 0;
        float elv = el[s_cur * 8 + h];
        ushort8_t fv = *(const ushort8_t*)(xb + (size_t)s_cur * 64 + j * 8);
        float v = elv + er_n;
        v = (v > 0.f) ? v : NEG_SLOPE * v;
        float z = __expf(v);
        denom += z;
        #pragma unroll
        for (int t = 0; t < 8; ++t) a[t] = fmaf(z, bf2f(fv[t]), a[t]);
        s_cur = s_nxt;
    }
    float inv = (end > beg) ? 1.f / denom : 0.f;
    ushort8_t o;
    #pragma unroll
    for (int t = 0; t < 8; ++t) o[t] = f2bf(a[t] * inv);
    *(ushort8_t*)(xagg + (size_t)node * 512 + lane * 8) = o;
}

// ---- bn1_stats: compute h tiles from xagg via MFMA (no store), accumulate BN1 sums ----
__global__ __launch_bounds__(256)
void bn1_stats(const unsigned short* __restrict__ Xa,
               const unsigned short* __restrict__ Fw,
               const float* __restrict__ gat_bias,
               float* __restrict__ sums1, int M)
{
    __shared__ alignas(16) char Asm[128 * 64 * 2];
    __shared__ alignas(16) char Bsm[64 * 64 * 2];
    __shared__ float reds[4][64], redq[4][64];
    const int tid = threadIdx.x, lane = tid & 63, wave = tid >> 6;
    const int bm = blockIdx.x * 128;
    const int head = blockIdx.y;
    const int lr = lane >> 3, lk = ((lane & 7) ^ lr) * 8;

    #pragma unroll
    for (int it = 0; it < 4; ++it) {
        int seg = wave * 4 + it;
        gload16(Xa + (size_t)(bm + seg * 8 + lr) * 512 + head * 64 + lk, Asm + seg * 1024);
    }
    #pragma unroll
    for (int it = 0; it < 2; ++it) {
        int seg = wave * 2 + it;
        gload16(Fw + (size_t)(head * 64 + seg * 8 + lr) * 64 + lk, Bsm + seg * 1024);
    }
    __syncthreads();

    f32x4 acc[2][4] = {};
    #pragma unroll
    for (int kk = 0; kk < 2; ++kk) {
        int kg = kk * 4 + (lane >> 4);
        bf16x8 a[2], b[4];
        #pragma unroll
        for (int i = 0; i < 2; ++i) {
            int row = wave * 32 + i * 16 + (lane & 15);
            a[i] = *(const bf16x8*)(Asm + row * 128 + ((kg ^ (row & 7)) << 4));
        }
        #pragma unroll
        for (int j = 0; j < 4; ++j) {
            int row = j * 16 + (lane & 15);
            b[j] = *(const bf16x8*)(Bsm + row * 128 + ((kg ^ (row & 7)) << 4));
        }
        #pragma unroll
        for (int i = 0; i < 2; ++i)
            #pragma unroll
            for (int j = 0; j < 4; ++j)
                acc[i][j] = __builtin_amdgcn_mfma_f32_16x16x32_bf16(a[i], b[j], acc[i][j], 0, 0, 0);
    }

    float s4[4] = {}, q4[4] = {};
    #pragma unroll
    for (int j = 0; j < 4; ++j) {
        int col = j * 16 + (lane & 15);
        float bias = gat_bias[head * 64 + col];
        #pragma unroll
        for (int i = 0; i < 2; ++i)
            #pragma unroll
            for (int r = 0; r < 4; ++r) {
                int gm = bm + wave * 32 + i * 16 + (lane >> 4) * 4 + r;
                if (gm < M) {
                    float vq = bf2f(f2bf(acc[i][j][r] + bias));
                    s4[j] += vq; q4[j] += vq * vq;
                }
            }
    }
    #pragma unroll
    for (int j = 0; j < 4; ++j) {
        s4[j] += __shfl_xor(s4[j], 16); q4[j] += __shfl_xor(q4[j], 16);
        s4[j] += __shfl_xor(s4[j], 32); q4[j] += __shfl_xor(q4[j], 32);
    }
    if (lane < 16) {
        #pragma unroll
        for (int j = 0; j < 4; ++j) {
            reds[wave][j * 16 + lane] = s4[j];
            redq[wave][j * 16 + lane] = q4[j];
        }
    }
    __syncthreads();
    if (wave == 0 && lane < 16) {
        #pragma unroll
        for (int j = 0; j < 4; ++j) {
            int c = j * 16 + lane;
            atomicAdd(&sums1[head * 64 + c], reds[0][c] + reds[1][c] + reds[2][c] + reds[3][c]);
            atomicAdd(&sums1[512 + head * 64 + c], redq[0][c] + redq[1][c] + redq[2][c] + redq[3][c]);
        }
    }
}

// ---- fold: W~[o,h*64+k] = sum_d (a*w1)[o,h*64+d]*fc_w[h*64+d][k];  b1p = b1 + w1@s ----
__global__ __launch_bounds__(256)
void fold(const float* __restrict__ w1, const float* __restrict__ fc_w,
          const float* __restrict__ sums1, const float* __restrict__ gamma,
          const float* __restrict__ beta, const float* __restrict__ gat_bias,
          const float* __restrict__ b1, unsigned short* __restrict__ wtil,
          float* __restrict__ b1p, float invM)
{
    const int bid = blockIdx.x, tid = threadIdx.x;
    if (bid < 64) {
        __shared__ float sF[64][65];
        __shared__ float sa[64];
        int ot = bid >> 3, h = bid & 7;
        if (tid < 64) {
            int c = h * 64 + tid;
            float mu = sums1[c] * invM;
            float var = sums1[512 + c] * invM - mu * mu;
            sa[tid] = gamma[c] * rsqrtf(var + BN_EPS);
        }
        for (int e = 0; e < 16; ++e) {
            int idx = tid * 16 + e;
            int d = idx >> 6, k = idx & 63;
            sF[k][d] = fc_w[(size_t)(h * 64 + d) * 64 + k];
        }
        __syncthreads();
        int ol = tid >> 1, half = tid & 1;
        int o = ot * 128 + ol;
        int kbase = half * 32;
        float acc[32];
        #pragma unroll
        for (int i = 0; i < 32; ++i) acc[i] = 0.f;
        const float* wrow = w1 + (size_t)o * 512 + h * 64;
        #pragma unroll
        for (int dc = 0; dc < 4; ++dc) {
            float wa[16];
            #pragma unroll
            for (int d = 0; d < 16; ++d) wa[d] = wrow[dc * 16 + d] * sa[dc * 16 + d];
            #pragma unroll
            for (int kk2 = 0; kk2 < 32; ++kk2) {
                float s = acc[kk2];
                #pragma unroll
                for (int d = 0; d < 16; ++d) s = fmaf(wa[d], sF[kbase + kk2][dc * 16 + d], s);
                acc[kk2] = s;
            }
        }
        unsigned int* orow = (unsigned int*)(wtil + (size_t)o * 512 + h * 64 + kbase);
        #pragma unroll
        for (int i = 0; i < 16; ++i)
            orow[i] = (unsigned int)f2bf(acc[2 * i]) | ((unsigned int)f2bf(acc[2 * i + 1]) << 16);
    } else {
        __shared__ float ss[512];
        for (int c = tid; c < 512; c += 256) {
            float mu = sums1[c] * invM;
            float var = sums1[512 + c] * invM - mu * mu;
            float a = gamma[c] * rsqrtf(var + BN_EPS);
            ss[c] = beta[c] + a * (gat_bias[c] - mu);
        }
        __syncthreads();
        int wave = tid >> 6, lane = tid & 63;
        int o = (bid - 64) * 4 + wave;
        const float* wrow = w1 + (size_t)o * 512 + lane * 8;
        float p = 0.f;
        #pragma unroll
        for (int t2 = 0; t2 < 8; ++t2) p = fmaf(wrow[t2], ss[lane * 8 + t2], p);
        #pragma unroll
        for (int d = 1; d < 64; d <<= 1) p += __shfl_xor(p, d);
        if (lane == 0) b1p[o] = b1[o] + p;
    }
}

// ---------------- GEMM2 + partial GEMM3, bf16 P-partial stores ----------------
__global__ __launch_bounds__(256)
void gemm2p(const unsigned short* __restrict__ A,   // xagg [Mpad,512]
            const unsigned short* __restrict__ B,   // wtil [1024,512]
            const unsigned short* __restrict__ W2,  // w2bf [64,1024]
            const float* __restrict__ b1p,          // [1024]
            unsigned short* __restrict__ P,         // [8][M][64] bf16 partials
            int M)
{
    __shared__ alignas(16) char smem[49152];
    char* Abuf0 = smem;
    char* Abuf1 = smem + 16384;
    char* Bbuf  = smem + 32768;
    char* TR   = smem;
    char* Wbuf = smem + 32768;
    char* PK   = smem + 32768;

    const int tid = threadIdx.x, lane = tid & 63, wave = tid >> 6;
    const int wr = wave >> 1, wc = wave & 1;
    const int lr = lane >> 3, lk = ((lane & 7) ^ lr) * 8;

    int bid = blockIdx.x;
    int wgid = (bid & 7) * 391 + (bid >> 3);
    const int bm = (wgid >> 3) * 128;
    const int t  = wgid & 7;
    const int bn = t * 128;

    #pragma unroll
    for (int it = 0; it < 4; ++it) {
        int seg = wave * 4 + it;
        gload16(A + (size_t)(bm + seg * 8 + lr) * 512 + lk, Abuf0 + seg * 1024);
    }

    f32x4 acc[4][4] = {};
    #pragma unroll
    for (int ks = 0; ks < 8; ++ks) {
        const int k0 = ks * 64;
        #pragma unroll
        for (int it = 0; it < 4; ++it) {
            int seg = wave * 4 + it;
            gload16(B + (size_t)(bn + seg * 8 + lr) * 512 + k0 + lk, Bbuf + seg * 1024);
        }
        if (ks < 7) {
            char* An = (ks & 1) ? Abuf0 : Abuf1;
            #pragma unroll
            for (int it = 0; it < 4; ++it) {
                int seg = wave * 4 + it;
                gload16(A + (size_t)(bm + seg * 8 + lr) * 512 + (k0 + 64) + lk, An + seg * 1024);
            }
            asm volatile("s_waitcnt vmcnt(4)" ::: "memory");
        } else {
            asm volatile("s_waitcnt vmcnt(0)" ::: "memory");
        }
        __builtin_amdgcn_s_barrier();
        __builtin_amdgcn_sched_barrier(0);
        const char* Ac = (ks & 1) ? Abuf1 : Abuf0;
        #pragma unroll
        for (int kk = 0; kk < 2; ++kk) {
            int kg = kk * 4 + (lane >> 4);
            bf16x8 a[4], b[4];
            #pragma unroll
            for (int i = 0; i < 4; ++i) {
                int row = wr * 64 + i * 16 + (lane & 15);
                a[i] = *(const bf16x8*)(Ac + row * 128 + ((kg ^ (row & 7)) << 4));
            }
            #pragma unroll
            for (int j = 0; j < 4; ++j) {
                int row = wc * 64 + j * 16 + (lane & 15);
                b[j] = *(const bf16x8*)(Bbuf + row * 128 + ((kg ^ (row & 7)) << 4));
            }
            #pragma unroll
            for (int i = 0; i < 4; ++i)
                #pragma unroll
                for (int j = 0; j < 4; ++j)
                    acc[i][j] = __builtin_amdgcn_mfma_f32_16x16x32_bf16(a[i], b[j], acc[i][j], 0, 0, 0);
        }
        __builtin_amdgcn_sched_barrier(0);
        __builtin_amdgcn_s_barrier();
        __builtin_amdgcn_sched_barrier(0);
    }

    // h1 tile (bias+relu+bf16) -> TR swizzled
    #pragma unroll
    for (int j = 0; j < 4; ++j) {
        int c = wc * 64 + j * 16 + (lane & 15);
        float bs = b1p[bn + c];
        #pragma unroll
        for (int i = 0; i < 4; ++i)
            #pragma unroll
            for (int r = 0; r < 4; ++r) {
                int rw = wr * 64 + i * 16 + (lane >> 4) * 4 + r;
                float v = fmaxf(acc[i][j][r] + bs, 0.f);
                *(unsigned short*)(TR + rw * 256 + (((c >> 3) ^ (rw & 7)) << 4) + (c & 7) * 2) = f2bf(v);
            }
    }
    #pragma unroll
    for (int it = 0; it < 4; ++it) {
        int oc = wave * 16 + it * 4 + (lane >> 4);
        int g = lane & 15;
        gload16(W2 + (size_t)oc * 1024 + bn + ((g ^ (oc & 7))) * 8, Wbuf + (wave * 4 + it) * 1024);
    }
    __syncthreads();

    f32x4 pacc[2][4] = {};
    #pragma unroll
    for (int ks = 0; ks < 4; ++ks) {
        int kg2 = ks * 4 + (lane >> 4);
        #pragma unroll
        for (int i = 0; i < 2; ++i) {
            int arow = wave * 32 + i * 16 + (lane & 15);
            bf16x8 av = *(const bf16x8*)(TR + arow * 256 + ((kg2 ^ (arow & 7)) << 4));
            #pragma unroll
            for (int j = 0; j < 4; ++j) {
                int oc = j * 16 + (lane & 15);
                bf16x8 bv = *(const bf16x8*)(Wbuf + oc * 256 + ((kg2 ^ (oc & 7)) << 4));
                pacc[i][j] = __builtin_amdgcn_mfma_f32_16x16x32_bf16(av, bv, pacc[i][j], 0, 0, 0);
            }
        }
    }
    __syncthreads();

    #pragma unroll
    for (int i = 0; i < 2; ++i)
        #pragma unroll
        for (int j = 0; j < 4; ++j)
            #pragma unroll
            for (int r = 0; r < 4; ++r) {
                int row = wave * 32 + i * 16 + (lane >> 4) * 4 + r;
                int col = j * 16 + (lane & 15);
                *(unsigned short*)(PK + row * 128 + col * 2) = f2bf(pacc[i][j][r]);
            }
    __syncthreads();
    unsigned short* Pt = P + (size_t)t * M * 64;
    #pragma unroll
    for (int it = 0; it < 4; ++it) {
        int u = it * 256 + tid;
        int row = u >> 3, g8 = u & 7;
        int gm = bm + row;
        if (gm < M) {
            uint4 v = *(const uint4*)(PK + row * 128 + g8 * 16);
            *(uint4*)(Pt + (size_t)gm * 64 + g8 * 8) = v;
        }
    }
}

// ---------------- reduce 8 bf16 partials + b2 -> out, fused BN2 stats ----------------
__global__ __launch_bounds__(256)
void reduce_bn2(const unsigned short* __restrict__ P, const float* __restrict__ b2,
                float* __restrict__ out, int M, float* __restrict__ sums2)
{
    __shared__ float ls[256], lq[256];
    int c = threadIdx.x & 63, g = threadIdx.x >> 6;
    const size_t S = (size_t)M * 64;
    float bias = b2[c];
    float s = 0.f, q = 0.f;
    for (int r = blockIdx.x * 4 + g; r < M; r += gridDim.x * 4) {
        size_t idx = (size_t)r * 64 + c;
        float v = bias;
        #pragma unroll
        for (int t = 0; t < 8; ++t) v += bf2f(P[t * S + idx]);
        out[idx] = v;
        s += v; q += v * v;
    }
    ls[threadIdx.x] = s; lq[threadIdx.x] = q;
    __syncthreads();
    if (g == 0) {
        s = ls[c] + ls[64 + c] + ls[128 + c] + ls[192 + c];
        q = lq[c] + lq[64 + c] + lq[128 + c] + lq[192 + c];
        atomicAdd(&sums2[c], s);
        atomicAdd(&sums2[64 + c], q);
    }
}

// ---------------- BN2 apply (finalize inlined per-thread) ----------------
__global__ __launch_bounds__(256)
void bn_apply64(float* __restrict__ X, const float* __restrict__ sums2,
                const float* __restrict__ gamma, const float* __restrict__ beta,
                int M, float invM)
{
    int c = threadIdx.x & 63, g = threadIdx.x >> 6;
    float mu = sums2[c] * invM;
    float var = sums2[64 + c] * invM - mu * mu;
    float a = gamma[c] * rsqrtf(var + BN_EPS);
    float b = beta[c] - a * mu;
    for (int r = blockIdx.x * 4 + g; r < M; r += gridDim.x * 4) {
        size_t i = (size_t)r * 64 + c;
        X[i] = fmaf(a, X[i], b);
    }
}

extern "C" void kernel_launch(void* const* d_in, const int* in_sizes, int n_in,
                              void* d_out, int out_size, void* d_ws, size_t ws_size,
                              hipStream_t stream)
{
    const float* x         = (const float*)d_in[0];
    const int*   src       = (const int*)d_in[1];
    const int*   dst       = (const int*)d_in[2];
    const float* fc_w      = (const float*)d_in[3];
    const float* attn_l    = (const float*)d_in[4];
    const float* attn_r    = (const float*)d_in[5];
    const float* gat_bias  = (const float*)d_in[6];
    const float* bn1_gamma = (const float*)d_in[7];
    const float* bn1_beta  = (const float*)d_in[8];
    const float* w1        = (const float*)d_in[9];
    const float* b1        = (const float*)d_in[10];
    const float* w2        = (const float*)d_in[11];
    const float* b2        = (const float*)d_in[12];
    const float* bn2_gamma = (const float*)d_in[13];
    const float* bn2_beta  = (const float*)d_in[14];
    float* out = (float*)d_out;

    const int D = 64, HD = 512, HID = 1024;
    const int N = in_sizes[0] / D;      // 50000
    const int E = in_sizes[1];          // 400000
    const int NH = N * 8;
    const int NB = (N + 255) / 256;     // 196
    const int Mpad = ((N + 127) / 128) * 128 + 128;  // 50176

    size_t off = 0;
    auto alloc = [&](size_t bytes) -> void* {
        void* p = (char*)d_ws + off;
        off += (bytes + 255) & ~(size_t)255;
        return p;
    };
    unsigned short* xagg = (unsigned short*)alloc((size_t)Mpad * HD * 2);
    unsigned short* P    = (unsigned short*)alloc((size_t)8 * N * D * 2);
    unsigned short* xbf  = (unsigned short*)alloc((size_t)N * D * 2);
    unsigned short* fcwbf = (unsigned short*)alloc((size_t)HD * D * 2);
    unsigned short* wtil = (unsigned short*)alloc((size_t)HID * HD * 2);
    unsigned short* w2bf = (unsigned short*)alloc((size_t)D * HID * 2);
    float* b1p   = (float*)alloc(HID * 4);
    float* proj  = (float*)alloc(2 * 512 * 4);
    float* el    = (float*)alloc((size_t)NH * 4);
    float* er    = (float*)alloc((size_t)NH * 4);
    // contiguous zero region: counts | sums1 | sums2 | bsum
    char* zbase  = (char*)d_ws + off;
    int* counts  = (int*)alloc((size_t)N * 4);
    float* sums1 = (float*)alloc(2 * 512 * 4);
    float* sums2 = (float*)alloc(2 * 64 * 4);
    int* bsum    = (int*)alloc(256 * 4);
    size_t zbytes = ((char*)d_ws + off) - zbase;
    int* row_ptr = (int*)alloc((size_t)(N + 1) * 4);
    int* cursor  = (int*)alloc((size_t)(N + 1) * 4);
    int* esrc    = (int*)alloc((size_t)E * 4);
    (void)ws_size; (void)n_in; (void)out_size;

    // 1) zero counts+sums+bsum
    hipMemsetAsync(zbase, 0, zbytes, stream);

    // 2) prep: cvt_x | hist | cvt_fcw | cvt_w2 | build_proj
    {
        int totX4 = (N * D) / 4;                     // 800000
        int bCvtx = (totX4 + 255) / 256;             // 3125
        int bHist = bCvtx + (E + 1023) / 1024;       // +391
        int bFcw  = bHist + 32;
        int bW2   = bFcw + 64;
        int grid  = bW2 + 1;
        prep<<<grid, 256, 0, stream>>>(x, dst, fc_w, w2, attn_l, attn_r,
                                       xbf, fcwbf, w2bf, proj, counts,
                                       totX4, E, bCvtx, bHist, bFcw, bW2);
    }

    // 3) single-pass scan (+cursor init) + elr
    scan_elr<<<NB + (NH + 255) / 256, 256, 0, stream>>>(counts, bsum, row_ptr, cursor,
                                                        N, NB, xbf, proj, el, er, NH);
    // 4) CSR scatter
    scatter_edges<<<(E + 255) / 256, 256, 0, stream>>>(src, dst, cursor, esrc, E);

    // 5) fused GAT softmax + aggregate of x -> xagg bf16
    gat_aggregate<<<(N + 3) / 4, 256, 0, stream>>>(row_ptr, esrc, el, er, xbf, xagg, N);

    // 6) BN1 stats (h computed on the fly, never stored)
    {
        dim3 grid((N + 127) / 128, 8);
        bn1_stats<<<grid, 256, 0, stream>>>(xagg, fcwbf, gat_bias, sums1, N);
    }
    // 7) fold W~ + b1p
    fold<<<320, 256, 0, stream>>>(w1, fc_w, sums1, bn1_gamma, bn1_beta, gat_bias,
                                  b1, wtil, b1p, 1.f / N);

    // 8) GEMM2 + partial GEMM3 -> bf16 P partials
    {
        int nwg = ((N + 127) / 128) * 8;  // 3128
        gemm2p<<<nwg, 256, 0, stream>>>(xagg, wtil, w2bf, b1p, P, N);
    }

    // 9) reduce partials + b2 -> out, BN2 stats
    reduce_bn2<<<1024, 256, 0, stream>>>(P, b2, out, N, sums2);
    // 10) BN2 apply
    bn_apply64<<<1024, 256, 0, stream>>>(out, sums2, bn2_gamma, bn2_beta, N, 1.f / N);
}